// Round 9
// baseline (1629.657 us; speedup 1.0000x reference)
//
#include <hip/hip_runtime.h>
#include <stdint.h>

// Problem constants
#define EMB   1024
#define HEADS 16
#define HD    64
#define BB    2
#define TT    2048
#define MTOT  (BB*TT)
#define LDA   72               // padded LDS stride for attention tiles
#define LDP   72               // padded LDS stride for GEMM tiles (144 B = 16B-aligned)

#define ELX (4194304u)         // MTOT*EMB elems
#define ELW (1048576u)         // EMB*EMB elems

#define CSCALE (0.125f * 1.44269504088896f)   // HD^-0.5 * log2(e)

typedef __attribute__((ext_vector_type(8))) short short8;
typedef __attribute__((ext_vector_type(4))) float f32x4;
typedef __attribute__((ext_vector_type(4))) unsigned short us4;

__device__ __forceinline__ float bf2f(ushort u) {
  union { uint32_t u; float f; } x; x.u = ((uint32_t)u) << 16; return x.f;
}
__device__ __forceinline__ ushort f2bf(float f) {
  union { float f; uint32_t u; } x; x.f = f;
  uint32_t u = x.u;
  u += 0x7fffu + ((u >> 16) & 1u);   // RNE
  return (ushort)(u >> 16);
}
__device__ __forceinline__ ushort f2bf_trunc(float f) {
  union { float f; uint32_t u; } x; x.f = f;
  return (ushort)(x.u >> 16);
}
__device__ __forceinline__ uint32_t pack2(uint32_t lo, uint32_t hi) {
  return (lo >> 16) | (hi & 0xFFFF0000u);   // [bf16(lo), bf16(hi)] truncation
}
__device__ __forceinline__ short8 pack8(f32x4 a, f32x4 b) {
  union { f32x4 v; uint32_t u[4]; } A, B;
  A.v = a; B.v = b;
  union { uint32_t d[4]; short8 s; } R;
  R.d[0] = pack2(A.u[0], A.u[1]);
  R.d[1] = pack2(A.u[2], A.u[3]);
  R.d[2] = pack2(B.u[0], B.u[1]);
  R.d[3] = pack2(B.u[2], B.u[3]);
  return R.s;
}
__device__ __forceinline__ short8 cvt8_rne(const float* f) {
  f32x4 a = *(const f32x4*)f;
  f32x4 b = *(const f32x4*)(f + 4);
  short8 r;
  r[0] = (short)f2bf(a[0]); r[1] = (short)f2bf(a[1]);
  r[2] = (short)f2bf(a[2]); r[3] = (short)f2bf(a[3]);
  r[4] = (short)f2bf(b[0]); r[5] = (short)f2bf(b[1]);
  r[6] = (short)f2bf(b[2]); r[7] = (short)f2bf(b[3]);
  return r;
}

// ---------------------------------------------------------------------------
// dtype probe (parallel): 1 = bf16 storage, 0 = fp32 storage
// ---------------------------------------------------------------------------
__global__ void detect_dtype(const uint32_t* __restrict__ x, int* __restrict__ flag) {
  const int lane = threadIdx.x & 63;
  int cnt = 0;
#pragma unroll
  for (int i = 0; i < 4; ++i) {
    const uint32_t v = x[lane * 4 + i];
    const uint32_t e = ((v & 0xFFFFu) >> 7) & 0xFFu;
    cnt += (e >= 0x70u && e <= 0x8Fu) ? 1 : 0;
  }
#pragma unroll
  for (int off = 1; off < 64; off <<= 1) cnt += __shfl_xor(cnt, off);
  if (lane == 0) *flag = (cnt > 128) ? 1 : 0;
}

// convert Wq,Wk,Wv -> contiguous bf16 [3*ELW] (RNE)   grid 1536 x 256
__global__ __launch_bounds__(256) void convert3(const void* __restrict__ w0,
                                                const void* __restrict__ w1,
                                                const void* __restrict__ w2,
                                                ushort* __restrict__ dst,
                                                const int* __restrict__ flag) {
  const size_t i = ((size_t)blockIdx.x * 256 + threadIdx.x) * 8;
  const int wi = (int)(i >> 20);
  const size_t off = i & (ELW - 1);
  const void* src = (wi == 0) ? w0 : (wi == 1) ? w1 : w2;
  if (*flag) *(short8*)(dst + i) = *(const short8*)((const ushort*)src + off);
  else       *(short8*)(dst + i) = cvt8_rne((const float*)src + off);
}

// ---------------------------------------------------------------------------
// QKV GEMM: 64x128 tile, BK=64, 16 iters, 3-set register rotation with
// prefetch distance 2 (no WAR: the set loaded at iter i was stored at i-1).
// ---------------------------------------------------------------------------
template<bool ABF>
__device__ __forceinline__ void gemm_qkv64(const void* __restrict__ Ap,
                                           const ushort* __restrict__ Wp,
                                           int m0, int n0,
                                           ushort* As, ushort* Ws,
                                           f32x4 acc[4][2]) {
  const int tid  = threadIdx.x;
  const int w    = tid >> 6;
  const int lane = tid & 63;
  const int quad = lane >> 4;
  const int l16  = lane & 15;
  const int arow = tid >> 2;            // 0..63
  const int acol = (tid & 3) * 16;      // 16 elems
  const int brow = tid >> 1;            // 0..127
  const int bcol = (tid & 1) * 32;      // 32 elems

  const size_t aoff = (size_t)(m0 + arow) * EMB + acol;
  const size_t boff = (size_t)(n0 + brow) * EMB + bcol;

  short8 ab[3][2];
  f32x4  af[3][4];
  short8 wb[3][4];

#pragma unroll
  for (int s = 0; s < 2; ++s) {
    if constexpr (ABF) {
      ab[s][0] = *(const short8*)((const ushort*)Ap + aoff + 64 * s);
      ab[s][1] = *(const short8*)((const ushort*)Ap + aoff + 64 * s + 8);
    } else {
#pragma unroll
      for (int i = 0; i < 4; ++i)
        af[s][i] = *(const f32x4*)((const float*)Ap + aoff + 64 * s + 4 * i);
    }
#pragma unroll
    for (int i = 0; i < 4; ++i)
      wb[s][i] = *(const short8*)(Wp + boff + 64 * s + 8 * i);
  }

#pragma unroll
  for (int it = 0; it < 16; ++it) {
    const int k0 = it * 64;
    const int cur = it % 3, nxt = (it + 2) % 3;
    __syncthreads();
    if constexpr (ABF) {
      *(short8*)&As[arow * LDP + acol]     = ab[cur][0];
      *(short8*)&As[arow * LDP + acol + 8] = ab[cur][1];
    } else {
      *(short8*)&As[arow * LDP + acol]     = pack8(af[cur][0], af[cur][1]);
      *(short8*)&As[arow * LDP + acol + 8] = pack8(af[cur][2], af[cur][3]);
    }
#pragma unroll
    for (int i = 0; i < 4; ++i) *(short8*)&Ws[brow * LDP + bcol + 8 * i] = wb[cur][i];
    if (it + 2 < 16) {
      const int kn = k0 + 128;
      if constexpr (ABF) {
        ab[nxt][0] = *(const short8*)((const ushort*)Ap + aoff + kn);
        ab[nxt][1] = *(const short8*)((const ushort*)Ap + aoff + kn + 8);
      } else {
#pragma unroll
        for (int i = 0; i < 4; ++i)
          af[nxt][i] = *(const f32x4*)((const float*)Ap + aoff + kn + 4 * i);
      }
#pragma unroll
      for (int i = 0; i < 4; ++i)
        wb[nxt][i] = *(const short8*)(Wp + boff + kn + 8 * i);
    }
    __syncthreads();

#pragma unroll
    for (int ks = 0; ks < 2; ++ks) {
      short8 a_[4], b_[2];
#pragma unroll
      for (int i = 0; i < 4; ++i)
        a_[i] = *(const short8*)&As[(i * 16 + l16) * LDP + ks * 32 + quad * 8];
#pragma unroll
      for (int i = 0; i < 2; ++i)
        b_[i] = *(const short8*)&Ws[(w * 32 + i * 16 + l16) * LDP + ks * 32 + quad * 8];
#pragma unroll
      for (int mi = 0; mi < 4; ++mi)
#pragma unroll
        for (int ni = 0; ni < 2; ++ni)
          acc[mi][ni] = __builtin_amdgcn_mfma_f32_16x16x32_bf16(a_[mi], b_[ni], acc[mi][ni], 0, 0, 0);
    }
  }
}

// QKV epilogue (64-row tile): Q (pre-scaled) / K head-major; V^T [B][H][HD][T]
__device__ __forceinline__ void qkv_epi64(f32x4 acc[4][2], int mt, int n0, int mat,
                                          const void* bias, int isbf,
                                          ushort* qo, ushort* ko, ushort* vo) {
  const int tid  = threadIdx.x;
  const int w    = tid >> 6;
  const int lane = tid & 63;
  const int quad = lane >> 4;
  const int l16  = lane & 15;
  ushort* dst = (mat == 0) ? qo : ko;
  const float sc = (mat == 0) ? CSCALE : 1.0f;

#pragma unroll
  for (int ni = 0; ni < 2; ++ni) {
    const int n = n0 + w * 32 + ni * 16 + l16;
    const float bv_ = isbf ? bf2f(((const ushort*)bias)[n]) : ((const float*)bias)[n];
    const int hh = n >> 6, d = n & 63;
#pragma unroll
    for (int mi = 0; mi < 4; ++mi) {
      const int mbase = mt * 64 + mi * 16 + quad * 4;
      const int b = mbase >> 11, t = mbase & (TT - 1);
      if (mat == 2) {
        us4 pk;
#pragma unroll
        for (int r = 0; r < 4; ++r) pk[r] = f2bf(acc[mi][ni][r] + bv_);
        *(us4*)&vo[((size_t)((b * HEADS + hh) * HD + d)) * TT + t] = pk;
      } else {
#pragma unroll
        for (int r = 0; r < 4; ++r)
          dst[((size_t)((b * HEADS + hh) * TT + t + r)) * HD + d] = f2bf((acc[mi][ni][r] + bv_) * sc);
      }
    }
  }
}

__global__ __launch_bounds__(256) void qkv_pipe(const void* __restrict__ x,
                                                const ushort* __restrict__ w3,
                                                const void* __restrict__ bq,
                                                const void* __restrict__ bk,
                                                const void* __restrict__ bv,
                                                ushort* __restrict__ qo,
                                                ushort* __restrict__ ko,
                                                ushort* __restrict__ vo,
                                                const int* __restrict__ flag) {
  __shared__ __align__(16) ushort As[64 * LDP];
  __shared__ __align__(16) ushort Ws[128 * LDP];
  // XCD swizzle: each XCD covers 3 n-tiles -> its W-slice stays L2-resident
  const int xcd = blockIdx.x & 7;
  const int i   = blockIdx.x >> 3;       // 0..191
  const int nt  = xcd * 3 + (i % 3);     // 0..23
  const int mt  = i / 3;                 // 0..63
  const int mat = nt >> 3;
  const int n0  = (nt & 7) * 128;
  const ushort* W  = w3 + (size_t)mat * ELW;
  const void* bias = (mat == 0) ? bq : (mat == 1) ? bk : bv;

  f32x4 acc[4][2];
#pragma unroll
  for (int a = 0; a < 4; ++a)
#pragma unroll
    for (int b = 0; b < 2; ++b) acc[a][b] = (f32x4){0.f, 0.f, 0.f, 0.f};

  const int isbf = *flag;
  if (isbf) gemm_qkv64<true >(x, W, mt * 64, n0, As, Ws, acc);
  else      gemm_qkv64<false>(x, W, mt * 64, n0, As, Ws, acc);
  qkv_epi64(acc, mt, n0, mat, bias, isbf, qo, ko, vo);
}

// ---------------------------------------------------------------------------
// Causal flash attention, 2-set WAR-free K/V register prefetch (distance 1).
// Fixed-max softmax. Balanced qt swizzle.
// ---------------------------------------------------------------------------
__global__ __launch_bounds__(256) void attn3(const ushort* __restrict__ qw,
                                             const ushort* __restrict__ kw,
                                             const ushort* __restrict__ vtw,
                                             ushort* __restrict__ out) {
  __shared__ __align__(16) ushort Ks[64 * LDA];
  __shared__ __align__(16) ushort Vts[64 * LDA];
  __shared__ __align__(16) ushort Ps[4][16 * LDA];

  const int bid = blockIdx.x;
  const int j  = bid >> 8;
  const int r8 = bid & 255;
  const int qh = r8 & 31;
  const int bh = j * 8 + (r8 >> 5);
  int qt;
  if      (j == 0) qt = qh;
  else if (j == 1) qt = 31 - qh;
  else if (j == 2) qt = (qh + 16) & 31;
  else             qt = 31 - ((qh + 16) & 31);
  const int h = bh & (HEADS - 1);
  const int b = bh >> 4;

  const int tid  = threadIdx.x;
  const int w    = tid >> 6;
  const int lane = tid & 63;
  const int quad = lane >> 4;
  const int l16  = lane & 15;

  const size_t hoff = ((size_t)(b * HEADS + h)) * TT * HD;
  const ushort* Qg = qw + hoff;
  const ushort* Kg = kw + hoff;
  const ushort* Vg = vtw + hoff;     // [d][T]
  const int q0 = qt * 64;

  short8 qf[2];
  {
    const ushort* qrow = Qg + (size_t)(q0 + w * 16 + l16) * HD;
    qf[0] = *(const short8*)(qrow + quad * 8);
    qf[1] = *(const short8*)(qrow + 32 + quad * 8);
  }

  const int row = tid >> 2;
  const int c0  = (tid & 3) * 16;
  const ushort* Kbase = Kg + (size_t)row * HD + c0;
  const ushort* Vbase = Vg + (size_t)row * TT + c0;

  // 2-set K/V prefetch registers
  short8 pk[2][2], pv[2][2];
  pk[0][0] = *(const short8*)(Kbase);
  pk[0][1] = *(const short8*)(Kbase + 8);
  pv[0][0] = *(const short8*)(Vbase);
  pv[0][1] = *(const short8*)(Vbase + 8);

  float ls[4] = {0.f, 0.f, 0.f, 0.f};
  f32x4 O[4];
#pragma unroll
  for (int ni = 0; ni < 4; ++ni) O[ni] = (f32x4){0.f, 0.f, 0.f, 0.f};

  for (int kt = 0; kt <= qt; ++kt) {
    const int k0 = kt * 64;
    const int cur = kt & 1, nxt = cur ^ 1;
    __syncthreads();
    *(short8*)&Ks[row * LDA + c0]      = pk[cur][0];
    *(short8*)&Ks[row * LDA + c0 + 8]  = pk[cur][1];
    *(short8*)&Vts[row * LDA + c0]     = pv[cur][0];
    *(short8*)&Vts[row * LDA + c0 + 8] = pv[cur][1];
    if (kt < qt) {        // load set 'nxt' (stored at kt-1 -> WAR-free)
      const size_t ko_ = (size_t)(k0 + 64) * HD;
      pk[nxt][0] = *(const short8*)(Kbase + ko_);
      pk[nxt][1] = *(const short8*)(Kbase + ko_ + 8);
      pv[nxt][0] = *(const short8*)(Vbase + k0 + 64);
      pv[nxt][1] = *(const short8*)(Vbase + k0 + 64 + 8);
    }
    __syncthreads();

    f32x4 s[4];
#pragma unroll
    for (int ni = 0; ni < 4; ++ni) s[ni] = (f32x4){0.f, 0.f, 0.f, 0.f};
#pragma unroll
    for (int ks = 0; ks < 2; ++ks) {
#pragma unroll
      for (int ni = 0; ni < 4; ++ni) {
        short8 kb = *(const short8*)&Ks[(ni * 16 + l16) * LDA + ks * 32 + quad * 8];
        s[ni] = __builtin_amdgcn_mfma_f32_16x16x32_bf16(qf[ks], kb, s[ni], 0, 0, 0);
      }
    }

    if (kt == qt) {
#pragma unroll
      for (int ni = 0; ni < 4; ++ni) {
        const int kk = k0 + ni * 16 + l16;
#pragma unroll
        for (int r = 0; r < 4; ++r) {
          const int qq = q0 + w * 16 + quad * 4 + r;
          if (kk > qq) s[ni][r] = -__builtin_inff();
        }
      }
    }

#pragma unroll
    for (int ni = 0; ni < 4; ++ni)
#pragma unroll
      for (int r = 0; r < 4; ++r) {
        const float p = exp2f(s[ni][r]);
        s[ni][r] = p;
        ls[r] += p;
      }

#pragma unroll
    for (int ni = 0; ni < 4; ++ni)
#pragma unroll
      for (int r = 0; r < 4; ++r)
        Ps[w][(quad * 4 + r) * LDA + ni * 16 + l16] = f2bf_trunc(s[ni][r]);

#pragma unroll
    for (int ks = 0; ks < 2; ++ks) {
      short8 a = *(const short8*)&Ps[w][l16 * LDA + ks * 32 + quad * 8];
#pragma unroll
      for (int ni = 0; ni < 4; ++ni) {
        short8 vb = *(const short8*)&Vts[(ni * 16 + l16) * LDA + ks * 32 + quad * 8];
        O[ni] = __builtin_amdgcn_mfma_f32_16x16x32_bf16(a, vb, O[ni], 0, 0, 0);
      }
    }
  }

#pragma unroll
  for (int r = 0; r < 4; ++r) {
#pragma unroll
    for (int off = 1; off < 16; off <<= 1) ls[r] += __shfl_xor(ls[r], off);
    const float inv = 1.0f / ls[r];
    const int t = q0 + w * 16 + quad * 4 + r;
#pragma unroll
    for (int ni = 0; ni < 4; ++ni) {
      out[((size_t)(b * TT + t)) * EMB + h * HD + ni * 16 + l16] = f2bf(O[ni][r] * inv);
    }
  }
}

// ---------------------------------------------------------------------------
// Output projection: 64x128 tile, BK=64 (16 iters, 16 MFMAs/pair), 3-set
// distance-2 register rotation. 512 blocks; bid&7 keeps n-tile per-XCD.
// ---------------------------------------------------------------------------
template<bool WBF>
__device__ __forceinline__ void proj_core(const ushort* __restrict__ A,
                                          const void* __restrict__ Wo,
                                          int m0, int n0,
                                          ushort* As, ushort* Ws,
                                          f32x4 acc[4][2]) {
  const int tid  = threadIdx.x;
  const int w    = tid >> 6;
  const int lane = tid & 63;
  const int quad = lane >> 4;
  const int l16  = lane & 15;
  const int arow = tid >> 2;            // 0..63
  const int acol = (tid & 3) * 16;
  const int brow = tid >> 1;            // 0..127
  const int bcol = (tid & 1) * 32;

  const size_t aoff = (size_t)(m0 + arow) * EMB + acol;
  const size_t boff = (size_t)(n0 + brow) * EMB + bcol;

  short8 ab[3][2];
  short8 wb[3][4];
  f32x4  wf[3][8];

#pragma unroll
  for (int s = 0; s < 2; ++s) {
    ab[s][0] = *(const short8*)(A + aoff + 64 * s);
    ab[s][1] = *(const short8*)(A + aoff + 64 * s + 8);
    if constexpr (WBF) {
#pragma unroll
      for (int i = 0; i < 4; ++i)
        wb[s][i] = *(const short8*)((const ushort*)Wo + boff + 64 * s + 8 * i);
    } else {
#pragma unroll
      for (int i = 0; i < 8; ++i)
        wf[s][i] = *(const f32x4*)((const float*)Wo + boff + 64 * s + 4 * i);
    }
  }

#pragma unroll
  for (int it = 0; it < 16; ++it) {
    const int k0 = it * 64;
    const int cur = it % 3, nxt = (it + 2) % 3;
    __syncthreads();
    *(short8*)&As[arow * LDP + acol]     = ab[cur][0];
    *(short8*)&As[arow * LDP + acol + 8] = ab[cur][1];
    if constexpr (WBF) {
#pragma unroll
      for (int i = 0; i < 4; ++i) *(short8*)&Ws[brow * LDP + bcol + 8 * i] = wb[cur][i];
    } else {
#pragma unroll
      for (int i = 0; i < 4; ++i)
        *(short8*)&Ws[brow * LDP + bcol + 8 * i] = pack8(wf[cur][2 * i], wf[cur][2 * i + 1]);
    }
    if (it + 2 < 16) {
      const int kn = k0 + 128;
      ab[nxt][0] = *(const short8*)(A + aoff + kn);
      ab[nxt][1] = *(const short8*)(A + aoff + kn + 8);
      if constexpr (WBF) {
#pragma unroll
        for (int i = 0; i < 4; ++i)
          wb[nxt][i] = *(const short8*)((const ushort*)Wo + boff + kn + 8 * i);
      } else {
#pragma unroll
        for (int i = 0; i < 8; ++i)
          wf[nxt][i] = *(const f32x4*)((const float*)Wo + boff + kn + 4 * i);
      }
    }
    __syncthreads();

#pragma unroll
    for (int ks = 0; ks < 2; ++ks) {
      short8 a_[4], b_[2];
#pragma unroll
      for (int i = 0; i < 4; ++i)
        a_[i] = *(const short8*)&As[(i * 16 + l16) * LDP + ks * 32 + quad * 8];
#pragma unroll
      for (int i = 0; i < 2; ++i)
        b_[i] = *(const short8*)&Ws[(w * 32 + i * 16 + l16) * LDP + ks * 32 + quad * 8];
#pragma unroll
      for (int mi = 0; mi < 4; ++mi)
#pragma unroll
        for (int ni = 0; ni < 2; ++ni)
          acc[mi][ni] = __builtin_amdgcn_mfma_f32_16x16x32_bf16(a_[mi], b_[ni], acc[mi][ni], 0, 0, 0);
    }
  }
}

__global__ __launch_bounds__(256) void proj_pipe(const ushort* __restrict__ A,
                                                 const void* __restrict__ Wo,
                                                 const void* __restrict__ bo,
                                                 void* __restrict__ out,
                                                 const int* __restrict__ flag) {
  __shared__ __align__(16) ushort As[64 * LDP];
  __shared__ __align__(16) ushort Ws[128 * LDP];
  const int nt = blockIdx.x & 7;         // consecutive bids -> different XCDs
  const int mt = blockIdx.x >> 3;
  const int n0 = nt * 128;
  const int m0 = mt * 64;

  f32x4 acc[4][2];
#pragma unroll
  for (int i = 0; i < 4; ++i)
#pragma unroll
    for (int jj = 0; jj < 2; ++jj) acc[i][jj] = (f32x4){0.f, 0.f, 0.f, 0.f};

  const int isbf = *flag;
  if (isbf) proj_core<true >(A, Wo, m0, n0, As, Ws, acc);
  else      proj_core<false>(A, Wo, m0, n0, As, Ws, acc);

  const int tid  = threadIdx.x;
  const int w    = tid >> 6;
  const int lane = tid & 63;
  const int quad = lane >> 4;
  const int l16  = lane & 15;

#pragma unroll
  for (int ni = 0; ni < 2; ++ni) {
    const int n = n0 + w * 32 + ni * 16 + l16;
    const float bv_ = isbf ? bf2f(((const ushort*)bo)[n]) : ((const float*)bo)[n];
#pragma unroll
    for (int mi = 0; mi < 4; ++mi) {
#pragma unroll
      for (int r = 0; r < 4; ++r) {
        const int m = m0 + mi * 16 + quad * 4 + r;
        const float v = acc[mi][ni][r] + bv_;
        if (isbf) ((ushort*)out)[(size_t)m * EMB + n] = f2bf(v);
        else      ((float*) out)[(size_t)m * EMB + n] = v;
      }
    }
  }
}

// ---------------------------------------------------------------------------
extern "C" void kernel_launch(void* const* d_in, const int* in_sizes, int n_in,
                              void* d_out, int out_size, void* d_ws, size_t ws_size,
                              hipStream_t stream) {
  const void* x  = d_in[0];
  const void* Wq = d_in[1];
  const void* bq = d_in[2];
  const void* Wk = d_in[3];
  const void* bk = d_in[4];
  const void* Wv = d_in[5];
  const void* bv = d_in[6];
  const void* Wo = d_in[7];
  const void* bo = d_in[8];

  int* flag = (int*)d_ws;
  ushort* base = (ushort*)((char*)d_ws + 256);

  // ws layout (33.56 MB budget):
  //   q:[0,ELX) k:[ELX,2ELX) vt:[2ELX,3ELX)
  //   w3 (3*ELW, dead after qkv) and o (ELX) share [3ELX,4ELX)
  ushort* q_ws  = base;
  ushort* k_ws  = q_ws + ELX;
  ushort* vt_ws = k_ws + ELX;
  ushort* w3    = vt_ws + ELX;
  ushort* o_ws  = vt_ws + ELX;

  detect_dtype<<<dim3(1), dim3(64), 0, stream>>>((const uint32_t*)x, flag);
  convert3<<<dim3(1536), dim3(256), 0, stream>>>(Wq, Wk, Wv, w3, flag);
  qkv_pipe<<<dim3(1536), dim3(256), 0, stream>>>(x, w3, bq, bk, bv,
                                                 q_ws, k_ws, vt_ws, flag);
  attn3<<<dim3(1024), dim3(256), 0, stream>>>(q_ws, k_ws, vt_ws, o_ws);
  proj_pipe<<<dim3(512), dim3(256), 0, stream>>>(o_ws, Wo, bo, d_out, flag);
}

// Round 10
// 232.699 us; speedup vs baseline: 7.0033x; 7.0033x over previous
//
#include <hip/hip_runtime.h>
#include <stdint.h>

// Problem constants
#define EMB   1024
#define HEADS 16
#define HD    64
#define BB    2
#define TT    2048
#define MTOT  (BB*TT)
#define LDA   72               // padded LDS stride for attention tiles
#define LDP   72               // padded LDS stride for GEMM tiles (144 B = 16B-aligned)

#define ELX (4194304u)         // MTOT*EMB elems
#define ELW (1048576u)         // EMB*EMB elems

#define CSCALE (0.125f * 1.44269504088896f)   // HD^-0.5 * log2(e)

typedef __attribute__((ext_vector_type(8))) short short8;
typedef __attribute__((ext_vector_type(4))) float f32x4;
typedef __attribute__((ext_vector_type(4))) unsigned short us4;

__device__ __forceinline__ float bf2f(ushort u) {
  union { uint32_t u; float f; } x; x.u = ((uint32_t)u) << 16; return x.f;
}
__device__ __forceinline__ ushort f2bf(float f) {
  union { float f; uint32_t u; } x; x.f = f;
  uint32_t u = x.u;
  u += 0x7fffu + ((u >> 16) & 1u);   // RNE
  return (ushort)(u >> 16);
}
__device__ __forceinline__ ushort f2bf_trunc(float f) {
  union { float f; uint32_t u; } x; x.f = f;
  return (ushort)(x.u >> 16);
}
__device__ __forceinline__ uint32_t pack2(uint32_t lo, uint32_t hi) {
  return (lo >> 16) | (hi & 0xFFFF0000u);   // [bf16(lo), bf16(hi)] truncation
}
__device__ __forceinline__ short8 pack8(f32x4 a, f32x4 b) {
  union { f32x4 v; uint32_t u[4]; } A, B;
  A.v = a; B.v = b;
  union { uint32_t d[4]; short8 s; } R;
  R.d[0] = pack2(A.u[0], A.u[1]);
  R.d[1] = pack2(A.u[2], A.u[3]);
  R.d[2] = pack2(B.u[0], B.u[1]);
  R.d[3] = pack2(B.u[2], B.u[3]);
  return R.s;
}
__device__ __forceinline__ short8 cvt8_rne(const float* f) {
  f32x4 a = *(const f32x4*)f;
  f32x4 b = *(const f32x4*)(f + 4);
  short8 r;
  r[0] = (short)f2bf(a[0]); r[1] = (short)f2bf(a[1]);
  r[2] = (short)f2bf(a[2]); r[3] = (short)f2bf(a[3]);
  r[4] = (short)f2bf(b[0]); r[5] = (short)f2bf(b[1]);
  r[6] = (short)f2bf(b[2]); r[7] = (short)f2bf(b[3]);
  return r;
}

// ---------------------------------------------------------------------------
// dtype probe (parallel): 1 = bf16 storage, 0 = fp32 storage
// ---------------------------------------------------------------------------
__global__ void detect_dtype(const uint32_t* __restrict__ x, int* __restrict__ flag) {
  const int lane = threadIdx.x & 63;
  int cnt = 0;
#pragma unroll
  for (int i = 0; i < 4; ++i) {
    const uint32_t v = x[lane * 4 + i];
    const uint32_t e = ((v & 0xFFFFu) >> 7) & 0xFFu;
    cnt += (e >= 0x70u && e <= 0x8Fu) ? 1 : 0;
  }
#pragma unroll
  for (int off = 1; off < 64; off <<= 1) cnt += __shfl_xor(cnt, off);
  if (lane == 0) *flag = (cnt > 128) ? 1 : 0;
}

// convert Wq,Wk,Wv -> contiguous bf16 [3*ELW] (RNE)   grid 1536 x 256
__global__ __launch_bounds__(256) void convert3(const void* __restrict__ w0,
                                                const void* __restrict__ w1,
                                                const void* __restrict__ w2,
                                                ushort* __restrict__ dst,
                                                const int* __restrict__ flag) {
  const size_t i = ((size_t)blockIdx.x * 256 + threadIdx.x) * 8;
  const int wi = (int)(i >> 20);
  const size_t off = i & (ELW - 1);
  const void* src = (wi == 0) ? w0 : (wi == 1) ? w1 : w2;
  if (*flag) *(short8*)(dst + i) = *(const short8*)((const ushort*)src + off);
  else       *(short8*)(dst + i) = cvt8_rne((const float*)src + off);
}

// ---------------------------------------------------------------------------
// QKV GEMM: 64x128 tile, BK=64, 16 iters (compile-time), 3-set register
// rotation distance 2. Set indices fold to constants under full unroll.
// ---------------------------------------------------------------------------
template<bool ABF>
__device__ __forceinline__ void gemm_qkv64(const void* __restrict__ Ap,
                                           const ushort* __restrict__ Wp,
                                           int m0, int n0,
                                           ushort* As, ushort* Ws,
                                           f32x4 acc[4][2]) {
  const int tid  = threadIdx.x;
  const int w    = tid >> 6;
  const int lane = tid & 63;
  const int quad = lane >> 4;
  const int l16  = lane & 15;
  const int arow = tid >> 2;            // 0..63
  const int acol = (tid & 3) * 16;      // 16 elems
  const int brow = tid >> 1;            // 0..127
  const int bcol = (tid & 1) * 32;      // 32 elems

  const size_t aoff = (size_t)(m0 + arow) * EMB + acol;
  const size_t boff = (size_t)(n0 + brow) * EMB + bcol;

  short8 ab[3][2];
  f32x4  af[3][4];
  short8 wb[3][4];

#pragma unroll
  for (int s = 0; s < 2; ++s) {
    if constexpr (ABF) {
      ab[s][0] = *(const short8*)((const ushort*)Ap + aoff + 64 * s);
      ab[s][1] = *(const short8*)((const ushort*)Ap + aoff + 64 * s + 8);
    } else {
#pragma unroll
      for (int i = 0; i < 4; ++i)
        af[s][i] = *(const f32x4*)((const float*)Ap + aoff + 64 * s + 4 * i);
    }
#pragma unroll
    for (int i = 0; i < 4; ++i)
      wb[s][i] = *(const short8*)(Wp + boff + 64 * s + 8 * i);
  }

#pragma unroll
  for (int it = 0; it < 16; ++it) {
    const int k0 = it * 64;
    const int cur = it % 3, nxt = (it + 2) % 3;
    __syncthreads();
    if constexpr (ABF) {
      *(short8*)&As[arow * LDP + acol]     = ab[cur][0];
      *(short8*)&As[arow * LDP + acol + 8] = ab[cur][1];
    } else {
      *(short8*)&As[arow * LDP + acol]     = pack8(af[cur][0], af[cur][1]);
      *(short8*)&As[arow * LDP + acol + 8] = pack8(af[cur][2], af[cur][3]);
    }
#pragma unroll
    for (int i = 0; i < 4; ++i) *(short8*)&Ws[brow * LDP + bcol + 8 * i] = wb[cur][i];
    if (it + 2 < 16) {
      const int kn = k0 + 128;
      if constexpr (ABF) {
        ab[nxt][0] = *(const short8*)((const ushort*)Ap + aoff + kn);
        ab[nxt][1] = *(const short8*)((const ushort*)Ap + aoff + kn + 8);
      } else {
#pragma unroll
        for (int i = 0; i < 4; ++i)
          af[nxt][i] = *(const f32x4*)((const float*)Ap + aoff + kn + 4 * i);
      }
#pragma unroll
      for (int i = 0; i < 4; ++i)
        wb[nxt][i] = *(const short8*)(Wp + boff + kn + 8 * i);
    }
    __syncthreads();

#pragma unroll
    for (int ks = 0; ks < 2; ++ks) {
      short8 a_[4], b_[2];
#pragma unroll
      for (int i = 0; i < 4; ++i)
        a_[i] = *(const short8*)&As[(i * 16 + l16) * LDP + ks * 32 + quad * 8];
#pragma unroll
      for (int i = 0; i < 2; ++i)
        b_[i] = *(const short8*)&Ws[(w * 32 + i * 16 + l16) * LDP + ks * 32 + quad * 8];
#pragma unroll
      for (int mi = 0; mi < 4; ++mi)
#pragma unroll
        for (int ni = 0; ni < 2; ++ni)
          acc[mi][ni] = __builtin_amdgcn_mfma_f32_16x16x32_bf16(a_[mi], b_[ni], acc[mi][ni], 0, 0, 0);
    }
  }
}

// QKV epilogue (64-row tile): Q (pre-scaled) / K head-major; V^T [B][H][HD][T]
__device__ __forceinline__ void qkv_epi64(f32x4 acc[4][2], int mt, int n0, int mat,
                                          const void* bias, int isbf,
                                          ushort* qo, ushort* ko, ushort* vo) {
  const int tid  = threadIdx.x;
  const int w    = tid >> 6;
  const int lane = tid & 63;
  const int quad = lane >> 4;
  const int l16  = lane & 15;
  ushort* dst = (mat == 0) ? qo : ko;
  const float sc = (mat == 0) ? CSCALE : 1.0f;

#pragma unroll
  for (int ni = 0; ni < 2; ++ni) {
    const int n = n0 + w * 32 + ni * 16 + l16;
    const float bv_ = isbf ? bf2f(((const ushort*)bias)[n]) : ((const float*)bias)[n];
    const int hh = n >> 6, d = n & 63;
#pragma unroll
    for (int mi = 0; mi < 4; ++mi) {
      const int mbase = mt * 64 + mi * 16 + quad * 4;
      const int b = mbase >> 11, t = mbase & (TT - 1);
      if (mat == 2) {
        us4 pk;
#pragma unroll
        for (int r = 0; r < 4; ++r) pk[r] = f2bf(acc[mi][ni][r] + bv_);
        *(us4*)&vo[((size_t)((b * HEADS + hh) * HD + d)) * TT + t] = pk;
      } else {
#pragma unroll
        for (int r = 0; r < 4; ++r)
          dst[((size_t)((b * HEADS + hh) * TT + t + r)) * HD + d] = f2bf((acc[mi][ni][r] + bv_) * sc);
      }
    }
  }
}

__global__ __launch_bounds__(256) void qkv_pipe(const void* __restrict__ x,
                                                const ushort* __restrict__ w3,
                                                const void* __restrict__ bq,
                                                const void* __restrict__ bk,
                                                const void* __restrict__ bv,
                                                ushort* __restrict__ qo,
                                                ushort* __restrict__ ko,
                                                ushort* __restrict__ vo,
                                                const int* __restrict__ flag) {
  __shared__ __align__(16) ushort As[64 * LDP];
  __shared__ __align__(16) ushort Ws[128 * LDP];
  // XCD swizzle: each XCD covers 3 n-tiles -> its W-slice stays L2-resident
  const int xcd = blockIdx.x & 7;
  const int i   = blockIdx.x >> 3;       // 0..191
  const int nt  = xcd * 3 + (i % 3);     // 0..23
  const int mt  = i / 3;                 // 0..63
  const int mat = nt >> 3;
  const int n0  = (nt & 7) * 128;
  const ushort* W  = w3 + (size_t)mat * ELW;
  const void* bias = (mat == 0) ? bq : (mat == 1) ? bk : bv;

  f32x4 acc[4][2];
#pragma unroll
  for (int a = 0; a < 4; ++a)
#pragma unroll
    for (int b = 0; b < 2; ++b) acc[a][b] = (f32x4){0.f, 0.f, 0.f, 0.f};

  const int isbf = *flag;
  if (isbf) gemm_qkv64<true >(x, W, mt * 64, n0, As, Ws, acc);
  else      gemm_qkv64<false>(x, W, mt * 64, n0, As, Ws, acc);
  qkv_epi64(acc, mt, n0, mat, bias, isbf, qo, ko, vo);
}

// ---------------------------------------------------------------------------
// Causal flash attention. 2-set prefetch with NAMED scalar sets and a
// manually 2x-unrolled kt loop (R9's runtime-indexed register arrays spilled
// to scratch: 1487 us, MfmaUtil 0.5%). All branches block-uniform.
// ---------------------------------------------------------------------------
__global__ __launch_bounds__(256) void attn3(const ushort* __restrict__ qw,
                                             const ushort* __restrict__ kw,
                                             const ushort* __restrict__ vtw,
                                             ushort* __restrict__ out) {
  __shared__ __align__(16) ushort Ks[64 * LDA];
  __shared__ __align__(16) ushort Vts[64 * LDA];
  __shared__ __align__(16) ushort Ps[4][16 * LDA];

  const int bid = blockIdx.x;
  const int j  = bid >> 8;
  const int r8 = bid & 255;
  const int qh = r8 & 31;
  const int bh = j * 8 + (r8 >> 5);
  int qt;
  if      (j == 0) qt = qh;
  else if (j == 1) qt = 31 - qh;
  else if (j == 2) qt = (qh + 16) & 31;
  else             qt = 31 - ((qh + 16) & 31);
  const int h = bh & (HEADS - 1);
  const int b = bh >> 4;

  const int tid  = threadIdx.x;
  const int w    = tid >> 6;
  const int lane = tid & 63;
  const int quad = lane >> 4;
  const int l16  = lane & 15;

  const size_t hoff = ((size_t)(b * HEADS + h)) * TT * HD;
  const ushort* Qg = qw + hoff;
  const ushort* Kg = kw + hoff;
  const ushort* Vg = vtw + hoff;     // [d][T]
  const int q0 = qt * 64;

  short8 qf[2];
  {
    const ushort* qrow = Qg + (size_t)(q0 + w * 16 + l16) * HD;
    qf[0] = *(const short8*)(qrow + quad * 8);
    qf[1] = *(const short8*)(qrow + 32 + quad * 8);
  }

  const int row = tid >> 2;
  const int c0  = (tid & 3) * 16;
  const ushort* Kbase = Kg + (size_t)row * HD + c0;   // + kt*64*HD
  const ushort* Vbase = Vg + (size_t)row * TT + c0;   // + kt*64

  float ls[4] = {0.f, 0.f, 0.f, 0.f};
  f32x4 O[4];
#pragma unroll
  for (int ni = 0; ni < 4; ++ni) O[ni] = (f32x4){0.f, 0.f, 0.f, 0.f};

  // per-tile compute: stage from LDS, QK^T, mask (diag only), exp2, PV
  auto compute_tile = [&](int kt) {
    f32x4 s[4];
#pragma unroll
    for (int ni = 0; ni < 4; ++ni) s[ni] = (f32x4){0.f, 0.f, 0.f, 0.f};
#pragma unroll
    for (int ks = 0; ks < 2; ++ks) {
#pragma unroll
      for (int ni = 0; ni < 4; ++ni) {
        short8 kb = *(const short8*)&Ks[(ni * 16 + l16) * LDA + ks * 32 + quad * 8];
        s[ni] = __builtin_amdgcn_mfma_f32_16x16x32_bf16(qf[ks], kb, s[ni], 0, 0, 0);
      }
    }
    if (kt == qt) {
#pragma unroll
      for (int ni = 0; ni < 4; ++ni) {
        const int kk = ni * 16 + l16;
#pragma unroll
        for (int r = 0; r < 4; ++r)
          if (kk > w * 16 + quad * 4 + r) s[ni][r] = -__builtin_inff();
      }
    }
#pragma unroll
    for (int ni = 0; ni < 4; ++ni)
#pragma unroll
      for (int r = 0; r < 4; ++r) {
        const float p = exp2f(s[ni][r]);
        s[ni][r] = p;
        ls[r] += p;
      }
#pragma unroll
    for (int ni = 0; ni < 4; ++ni)
#pragma unroll
      for (int r = 0; r < 4; ++r)
        Ps[w][(quad * 4 + r) * LDA + ni * 16 + l16] = f2bf_trunc(s[ni][r]);
#pragma unroll
    for (int ks = 0; ks < 2; ++ks) {
      short8 a = *(const short8*)&Ps[w][l16 * LDA + ks * 32 + quad * 8];
#pragma unroll
      for (int ni = 0; ni < 4; ++ni) {
        short8 vb = *(const short8*)&Vts[(ni * 16 + l16) * LDA + ks * 32 + quad * 8];
        O[ni] = __builtin_amdgcn_mfma_f32_16x16x32_bf16(a, vb, O[ni], 0, 0, 0);
      }
    }
  };

  // named prefetch sets (no dynamic indexing -> stays in VGPRs)
  short8 ak0, ak1, av0, av1;   // set A
  short8 bk0, bk1, bv0, bv1;   // set B

  // preload set A for kt=0
  ak0 = *(const short8*)(Kbase);
  ak1 = *(const short8*)(Kbase + 8);
  av0 = *(const short8*)(Vbase);
  av1 = *(const short8*)(Vbase + 8);

  for (int kt = 0; kt <= qt; ) {
    // --- even step: consume set A, prefetch set B for kt+1 ---
    __syncthreads();
    *(short8*)&Ks[row * LDA + c0]      = ak0;
    *(short8*)&Ks[row * LDA + c0 + 8]  = ak1;
    *(short8*)&Vts[row * LDA + c0]     = av0;
    *(short8*)&Vts[row * LDA + c0 + 8] = av1;
    if (kt + 1 <= qt) {
      const size_t ko_ = (size_t)(kt + 1) * 64 * HD;
      bk0 = *(const short8*)(Kbase + ko_);
      bk1 = *(const short8*)(Kbase + ko_ + 8);
      bv0 = *(const short8*)(Vbase + (kt + 1) * 64);
      bv1 = *(const short8*)(Vbase + (kt + 1) * 64 + 8);
    }
    __syncthreads();
    compute_tile(kt);
    ++kt;
    if (kt > qt) break;

    // --- odd step: consume set B, prefetch set A for kt+1 ---
    __syncthreads();
    *(short8*)&Ks[row * LDA + c0]      = bk0;
    *(short8*)&Ks[row * LDA + c0 + 8]  = bk1;
    *(short8*)&Vts[row * LDA + c0]     = bv0;
    *(short8*)&Vts[row * LDA + c0 + 8] = bv1;
    if (kt + 1 <= qt) {
      const size_t ko_ = (size_t)(kt + 1) * 64 * HD;
      ak0 = *(const short8*)(Kbase + ko_);
      ak1 = *(const short8*)(Kbase + ko_ + 8);
      av0 = *(const short8*)(Vbase + (kt + 1) * 64);
      av1 = *(const short8*)(Vbase + (kt + 1) * 64 + 8);
    }
    __syncthreads();
    compute_tile(kt);
    ++kt;
  }

#pragma unroll
  for (int r = 0; r < 4; ++r) {
#pragma unroll
    for (int off = 1; off < 16; off <<= 1) ls[r] += __shfl_xor(ls[r], off);
    const float inv = 1.0f / ls[r];
    const int t = q0 + w * 16 + quad * 4 + r;
#pragma unroll
    for (int ni = 0; ni < 4; ++ni) {
      out[((size_t)(b * TT + t)) * EMB + h * HD + ni * 16 + l16] = f2bf(O[ni][r] * inv);
    }
  }
}

// ---------------------------------------------------------------------------
// Output projection: 64x128 tile, BK=64 (16 compile-time iters), 3-set
// distance-2 register rotation. 512 blocks; bid&7 spreads n-tiles over XCDs.
// ---------------------------------------------------------------------------
template<bool WBF>
__device__ __forceinline__ void proj_core(const ushort* __restrict__ A,
                                          const void* __restrict__ Wo,
                                          int m0, int n0,
                                          ushort* As, ushort* Ws,
                                          f32x4 acc[4][2]) {
  const int tid  = threadIdx.x;
  const int w    = tid >> 6;
  const int lane = tid & 63;
  const int quad = lane >> 4;
  const int l16  = lane & 15;
  const int arow = tid >> 2;            // 0..63
  const int acol = (tid & 3) * 16;
  const int brow = tid >> 1;            // 0..127
  const int bcol = (tid & 1) * 32;

  const size_t aoff = (size_t)(m0 + arow) * EMB + acol;
  const size_t boff = (size_t)(n0 + brow) * EMB + bcol;

  short8 ab[3][2];
  short8 wb[3][4];
  f32x4  wf[3][8];

#pragma unroll
  for (int s = 0; s < 2; ++s) {
    ab[s][0] = *(const short8*)(A + aoff + 64 * s);
    ab[s][1] = *(const short8*)(A + aoff + 64 * s + 8);
    if constexpr (WBF) {
#pragma unroll
      for (int i = 0; i < 4; ++i)
        wb[s][i] = *(const short8*)((const ushort*)Wo + boff + 64 * s + 8 * i);
    } else {
#pragma unroll
      for (int i = 0; i < 8; ++i)
        wf[s][i] = *(const f32x4*)((const float*)Wo + boff + 64 * s + 4 * i);
    }
  }

#pragma unroll
  for (int it = 0; it < 16; ++it) {
    const int k0 = it * 64;
    const int cur = it % 3, nxt = (it + 2) % 3;
    __syncthreads();
    *(short8*)&As[arow * LDP + acol]     = ab[cur][0];
    *(short8*)&As[arow * LDP + acol + 8] = ab[cur][1];
    if constexpr (WBF) {
#pragma unroll
      for (int i = 0; i < 4; ++i) *(short8*)&Ws[brow * LDP + bcol + 8 * i] = wb[cur][i];
    } else {
#pragma unroll
      for (int i = 0; i < 4; ++i)
        *(short8*)&Ws[brow * LDP + bcol + 8 * i] = pack8(wf[cur][2 * i], wf[cur][2 * i + 1]);
    }
    if (it + 2 < 16) {
      const int kn = k0 + 128;
      ab[nxt][0] = *(const short8*)(A + aoff + kn);
      ab[nxt][1] = *(const short8*)(A + aoff + kn + 8);
      if constexpr (WBF) {
#pragma unroll
        for (int i = 0; i < 4; ++i)
          wb[nxt][i] = *(const short8*)((const ushort*)Wo + boff + kn + 8 * i);
      } else {
#pragma unroll
        for (int i = 0; i < 8; ++i)
          wf[nxt][i] = *(const f32x4*)((const float*)Wo + boff + kn + 4 * i);
      }
    }
    __syncthreads();

#pragma unroll
    for (int ks = 0; ks < 2; ++ks) {
      short8 a_[4], b_[2];
#pragma unroll
      for (int i = 0; i < 4; ++i)
        a_[i] = *(const short8*)&As[(i * 16 + l16) * LDP + ks * 32 + quad * 8];
#pragma unroll
      for (int i = 0; i < 2; ++i)
        b_[i] = *(const short8*)&Ws[(w * 32 + i * 16 + l16) * LDP + ks * 32 + quad * 8];
#pragma unroll
      for (int mi = 0; mi < 4; ++mi)
#pragma unroll
        for (int ni = 0; ni < 2; ++ni)
          acc[mi][ni] = __builtin_amdgcn_mfma_f32_16x16x32_bf16(a_[mi], b_[ni], acc[mi][ni], 0, 0, 0);
    }
  }
}

__global__ __launch_bounds__(256) void proj_pipe(const ushort* __restrict__ A,
                                                 const void* __restrict__ Wo,
                                                 const void* __restrict__ bo,
                                                 void* __restrict__ out,
                                                 const int* __restrict__ flag) {
  __shared__ __align__(16) ushort As[64 * LDP];
  __shared__ __align__(16) ushort Ws[128 * LDP];
  const int nt = blockIdx.x & 7;         // consecutive bids -> different XCDs
  const int mt = blockIdx.x >> 3;
  const int n0 = nt * 128;
  const int m0 = mt * 64;

  f32x4 acc[4][2];
#pragma unroll
  for (int i = 0; i < 4; ++i)
#pragma unroll
    for (int jj = 0; jj < 2; ++jj) acc[i][jj] = (f32x4){0.f, 0.f, 0.f, 0.f};

  const int isbf = *flag;
  if (isbf) proj_core<true >(A, Wo, m0, n0, As, Ws, acc);
  else      proj_core<false>(A, Wo, m0, n0, As, Ws, acc);

  const int tid  = threadIdx.x;
  const int w    = tid >> 6;
  const int lane = tid & 63;
  const int quad = lane >> 4;
  const int l16  = lane & 15;

#pragma unroll
  for (int ni = 0; ni < 2; ++ni) {
    const int n = n0 + w * 32 + ni * 16 + l16;
    const float bv_ = isbf ? bf2f(((const ushort*)bo)[n]) : ((const float*)bo)[n];
#pragma unroll
    for (int mi = 0; mi < 4; ++mi) {
#pragma unroll
      for (int r = 0; r < 4; ++r) {
        const int m = m0 + mi * 16 + quad * 4 + r;
        const float v = acc[mi][ni][r] + bv_;
        if (isbf) ((ushort*)out)[(size_t)m * EMB + n] = f2bf(v);
        else      ((float*) out)[(size_t)m * EMB + n] = v;
      }
    }
  }
}

// ---------------------------------------------------------------------------
extern "C" void kernel_launch(void* const* d_in, const int* in_sizes, int n_in,
                              void* d_out, int out_size, void* d_ws, size_t ws_size,
                              hipStream_t stream) {
  const void* x  = d_in[0];
  const void* Wq = d_in[1];
  const void* bq = d_in[2];
  const void* Wk = d_in[3];
  const void* bk = d_in[4];
  const void* Wv = d_in[5];
  const void* bv = d_in[6];
  const void* Wo = d_in[7];
  const void* bo = d_in[8];

  int* flag = (int*)d_ws;
  ushort* base = (ushort*)((char*)d_ws + 256);

  // ws layout (33.56 MB budget):
  //   q:[0,ELX) k:[ELX,2ELX) vt:[2ELX,3ELX)
  //   w3 (3*ELW, dead after qkv) and o (ELX) share [3ELX,4ELX)
  ushort* q_ws  = base;
  ushort* k_ws  = q_ws + ELX;
  ushort* vt_ws = k_ws + ELX;
  ushort* w3    = vt_ws + ELX;
  ushort* o_ws  = vt_ws + ELX;

  detect_dtype<<<dim3(1), dim3(64), 0, stream>>>((const uint32_t*)x, flag);
  convert3<<<dim3(1536), dim3(256), 0, stream>>>(Wq, Wk, Wv, w3, flag);
  qkv_pipe<<<dim3(1536), dim3(256), 0, stream>>>(x, w3, bq, bk, bv,
                                                 q_ws, k_ws, vt_ws, flag);
  attn3<<<dim3(1024), dim3(256), 0, stream>>>(q_ws, k_ws, vt_ws, o_ws);
  proj_pipe<<<dim3(512), dim3(256), 0, stream>>>(o_ws, Wo, bo, d_out, flag);
}

// Round 11
// 218.281 us; speedup vs baseline: 7.4659x; 1.0661x over previous
//
#include <hip/hip_runtime.h>
#include <stdint.h>

// Problem constants
#define EMB   1024
#define HEADS 16
#define HD    64
#define BB    2
#define TT    2048
#define MTOT  (BB*TT)
#define LDA   72               // padded LDS stride for attention tiles
#define LDP   72               // padded LDS stride for GEMM tiles

#define ELX (4194304u)         // MTOT*EMB elems
#define ELW (1048576u)         // EMB*EMB elems

#define CSCALE (0.125f * 1.44269504088896f)   // HD^-0.5 * log2(e)

typedef __attribute__((ext_vector_type(8))) short short8;
typedef __attribute__((ext_vector_type(4))) float f32x4;
typedef __attribute__((ext_vector_type(4))) unsigned short us4;

__device__ __forceinline__ float bf2f(ushort u) {
  union { uint32_t u; float f; } x; x.u = ((uint32_t)u) << 16; return x.f;
}
__device__ __forceinline__ ushort f2bf(float f) {
  union { float f; uint32_t u; } x; x.f = f;
  uint32_t u = x.u;
  u += 0x7fffu + ((u >> 16) & 1u);   // RNE
  return (ushort)(u >> 16);
}
__device__ __forceinline__ uint32_t pack2(uint32_t lo, uint32_t hi) {
  return (lo >> 16) | (hi & 0xFFFF0000u);   // [bf16(lo), bf16(hi)] truncation
}
__device__ __forceinline__ short8 pack8(f32x4 a, f32x4 b) {
  union { f32x4 v; uint32_t u[4]; } A, B;
  A.v = a; B.v = b;
  union { uint32_t d[4]; short8 s; } R;
  R.d[0] = pack2(A.u[0], A.u[1]);
  R.d[1] = pack2(A.u[2], A.u[3]);
  R.d[2] = pack2(B.u[0], B.u[1]);
  R.d[3] = pack2(B.u[2], B.u[3]);
  return R.s;
}
__device__ __forceinline__ short8 cvt8_rne(const float* f) {
  f32x4 a = *(const f32x4*)f;
  f32x4 b = *(const f32x4*)(f + 4);
  short8 r;
  r[0] = (short)f2bf(a[0]); r[1] = (short)f2bf(a[1]);
  r[2] = (short)f2bf(a[2]); r[3] = (short)f2bf(a[3]);
  r[4] = (short)f2bf(b[0]); r[5] = (short)f2bf(b[1]);
  r[6] = (short)f2bf(b[2]); r[7] = (short)f2bf(b[3]);
  return r;
}

// ---------------------------------------------------------------------------
// dtype probe (parallel): 1 = bf16 storage, 0 = fp32 storage
// ---------------------------------------------------------------------------
__global__ void detect_dtype(const uint32_t* __restrict__ x, int* __restrict__ flag) {
  const int lane = threadIdx.x & 63;
  int cnt = 0;
#pragma unroll
  for (int i = 0; i < 4; ++i) {
    const uint32_t v = x[lane * 4 + i];
    const uint32_t e = ((v & 0xFFFFu) >> 7) & 0xFFu;
    cnt += (e >= 0x70u && e <= 0x8Fu) ? 1 : 0;
  }
#pragma unroll
  for (int off = 1; off < 64; off <<= 1) cnt += __shfl_xor(cnt, off);
  if (lane == 0) *flag = (cnt > 128) ? 1 : 0;
}

// convert Wq,Wk,Wv -> contiguous bf16 [3*ELW] (RNE)   grid 1536 x 256
__global__ __launch_bounds__(256) void convert3(const void* __restrict__ w0,
                                                const void* __restrict__ w1,
                                                const void* __restrict__ w2,
                                                ushort* __restrict__ dst,
                                                const int* __restrict__ flag) {
  const size_t i = ((size_t)blockIdx.x * 256 + threadIdx.x) * 8;
  const int wi = (int)(i >> 20);
  const size_t off = i & (ELW - 1);
  const void* src = (wi == 0) ? w0 : (wi == 1) ? w1 : w2;
  if (*flag) *(short8*)(dst + i) = *(const short8*)((const ushort*)src + off);
  else       *(short8*)(dst + i) = cvt8_rne((const float*)src + off);
}

// ---------------------------------------------------------------------------
// QKV GEMM (unchanged from R10): 64x128 tile, BK=64, 3-set rotation.
// ---------------------------------------------------------------------------
template<bool ABF>
__device__ __forceinline__ void gemm_qkv64(const void* __restrict__ Ap,
                                           const ushort* __restrict__ Wp,
                                           int m0, int n0,
                                           ushort* As, ushort* Ws,
                                           f32x4 acc[4][2]) {
  const int tid  = threadIdx.x;
  const int w    = tid >> 6;
  const int lane = tid & 63;
  const int quad = lane >> 4;
  const int l16  = lane & 15;
  const int arow = tid >> 2;            // 0..63
  const int acol = (tid & 3) * 16;
  const int brow = tid >> 1;            // 0..127
  const int bcol = (tid & 1) * 32;

  const size_t aoff = (size_t)(m0 + arow) * EMB + acol;
  const size_t boff = (size_t)(n0 + brow) * EMB + bcol;

  short8 ab[3][2];
  f32x4  af[3][4];
  short8 wb[3][4];

#pragma unroll
  for (int s = 0; s < 2; ++s) {
    if constexpr (ABF) {
      ab[s][0] = *(const short8*)((const ushort*)Ap + aoff + 64 * s);
      ab[s][1] = *(const short8*)((const ushort*)Ap + aoff + 64 * s + 8);
    } else {
#pragma unroll
      for (int i = 0; i < 4; ++i)
        af[s][i] = *(const f32x4*)((const float*)Ap + aoff + 64 * s + 4 * i);
    }
#pragma unroll
    for (int i = 0; i < 4; ++i)
      wb[s][i] = *(const short8*)(Wp + boff + 64 * s + 8 * i);
  }

#pragma unroll
  for (int it = 0; it < 16; ++it) {
    const int k0 = it * 64;
    const int cur = it % 3, nxt = (it + 2) % 3;
    __syncthreads();
    if constexpr (ABF) {
      *(short8*)&As[arow * LDP + acol]     = ab[cur][0];
      *(short8*)&As[arow * LDP + acol + 8] = ab[cur][1];
    } else {
      *(short8*)&As[arow * LDP + acol]     = pack8(af[cur][0], af[cur][1]);
      *(short8*)&As[arow * LDP + acol + 8] = pack8(af[cur][2], af[cur][3]);
    }
#pragma unroll
    for (int i = 0; i < 4; ++i) *(short8*)&Ws[brow * LDP + bcol + 8 * i] = wb[cur][i];
    if (it + 2 < 16) {
      const int kn = k0 + 128;
      if constexpr (ABF) {
        ab[nxt][0] = *(const short8*)((const ushort*)Ap + aoff + kn);
        ab[nxt][1] = *(const short8*)((const ushort*)Ap + aoff + kn + 8);
      } else {
#pragma unroll
        for (int i = 0; i < 4; ++i)
          af[nxt][i] = *(const f32x4*)((const float*)Ap + aoff + kn + 4 * i);
      }
#pragma unroll
      for (int i = 0; i < 4; ++i)
        wb[nxt][i] = *(const short8*)(Wp + boff + kn + 8 * i);
    }
    __syncthreads();

#pragma unroll
    for (int ks = 0; ks < 2; ++ks) {
      short8 a_[4], b_[2];
#pragma unroll
      for (int i = 0; i < 4; ++i)
        a_[i] = *(const short8*)&As[(i * 16 + l16) * LDP + ks * 32 + quad * 8];
#pragma unroll
      for (int i = 0; i < 2; ++i)
        b_[i] = *(const short8*)&Ws[(w * 32 + i * 16 + l16) * LDP + ks * 32 + quad * 8];
#pragma unroll
      for (int mi = 0; mi < 4; ++mi)
#pragma unroll
        for (int ni = 0; ni < 2; ++ni)
          acc[mi][ni] = __builtin_amdgcn_mfma_f32_16x16x32_bf16(a_[mi], b_[ni], acc[mi][ni], 0, 0, 0);
    }
  }
}

__device__ __forceinline__ void qkv_epi64(f32x4 acc[4][2], int mt, int n0, int mat,
                                          const void* bias, int isbf,
                                          ushort* qo, ushort* ko, ushort* vo) {
  const int tid  = threadIdx.x;
  const int w    = tid >> 6;
  const int lane = tid & 63;
  const int quad = lane >> 4;
  const int l16  = lane & 15;
  ushort* dst = (mat == 0) ? qo : ko;
  const float sc = (mat == 0) ? CSCALE : 1.0f;

#pragma unroll
  for (int ni = 0; ni < 2; ++ni) {
    const int n = n0 + w * 32 + ni * 16 + l16;
    const float bv_ = isbf ? bf2f(((const ushort*)bias)[n]) : ((const float*)bias)[n];
    const int hh = n >> 6, d = n & 63;
#pragma unroll
    for (int mi = 0; mi < 4; ++mi) {
      const int mbase = mt * 64 + mi * 16 + quad * 4;
      const int b = mbase >> 11, t = mbase & (TT - 1);
      if (mat == 2) {
        us4 pk;
#pragma unroll
        for (int r = 0; r < 4; ++r) pk[r] = f2bf(acc[mi][ni][r] + bv_);
        *(us4*)&vo[((size_t)((b * HEADS + hh) * HD + d)) * TT + t] = pk;
      } else {
#pragma unroll
        for (int r = 0; r < 4; ++r)
          dst[((size_t)((b * HEADS + hh) * TT + t + r)) * HD + d] = f2bf((acc[mi][ni][r] + bv_) * sc);
      }
    }
  }
}

__global__ __launch_bounds__(256) void qkv_pipe(const void* __restrict__ x,
                                                const ushort* __restrict__ w3,
                                                const void* __restrict__ bq,
                                                const void* __restrict__ bk,
                                                const void* __restrict__ bv,
                                                ushort* __restrict__ qo,
                                                ushort* __restrict__ ko,
                                                ushort* __restrict__ vo,
                                                const int* __restrict__ flag) {
  __shared__ __align__(16) ushort As[64 * LDP];
  __shared__ __align__(16) ushort Ws[128 * LDP];
  const int xcd = blockIdx.x & 7;
  const int i   = blockIdx.x >> 3;       // 0..191
  const int nt  = xcd * 3 + (i % 3);     // 0..23
  const int mt  = i / 3;                 // 0..63
  const int mat = nt >> 3;
  const int n0  = (nt & 7) * 128;
  const ushort* W  = w3 + (size_t)mat * ELW;
  const void* bias = (mat == 0) ? bq : (mat == 1) ? bk : bv;

  f32x4 acc[4][2];
#pragma unroll
  for (int a = 0; a < 4; ++a)
#pragma unroll
    for (int b = 0; b < 2; ++b) acc[a][b] = (f32x4){0.f, 0.f, 0.f, 0.f};

  const int isbf = *flag;
  if (isbf) gemm_qkv64<true >(x, W, mt * 64, n0, As, Ws, acc);
  else      gemm_qkv64<false>(x, W, mt * 64, n0, As, Ws, acc);
  qkv_epi64(acc, mt, n0, mat, bias, isbf, qo, ko, vo);
}

// ---------------------------------------------------------------------------
// Causal flash attention with S^T trick: QK MFMA computes S^T (A=K, B=Q), so
// keys land in the register dim -> P transpose is 8 pack2 + 4 ds_write_b64
// (was 16 ds_write_b16 + 16 f2bf). ls is one accumulator/lane (q = l16).
// Named 2-set K/V prefetch, fixed-max softmax, balanced qt swizzle.
// ---------------------------------------------------------------------------
__global__ __launch_bounds__(256) void attn3(const ushort* __restrict__ qw,
                                             const ushort* __restrict__ kw,
                                             const ushort* __restrict__ vtw,
                                             ushort* __restrict__ out) {
  __shared__ __align__(16) ushort Ks[64 * LDA];
  __shared__ __align__(16) ushort Vts[64 * LDA];
  __shared__ __align__(16) ushort Ps[4][16 * LDA];

  const int bid = blockIdx.x;
  const int j  = bid >> 8;
  const int r8 = bid & 255;
  const int qh = r8 & 31;
  const int bh = j * 8 + (r8 >> 5);
  int qt;
  if      (j == 0) qt = qh;
  else if (j == 1) qt = 31 - qh;
  else if (j == 2) qt = (qh + 16) & 31;
  else             qt = 31 - ((qh + 16) & 31);
  const int h = bh & (HEADS - 1);
  const int b = bh >> 4;

  const int tid  = threadIdx.x;
  const int w    = tid >> 6;
  const int lane = tid & 63;
  const int quad = lane >> 4;
  const int l16  = lane & 15;

  const size_t hoff = ((size_t)(b * HEADS + h)) * TT * HD;
  const ushort* Qg = qw + hoff;
  const ushort* Kg = kw + hoff;
  const ushort* Vg = vtw + hoff;     // [d][T]
  const int q0 = qt * 64;

  short8 qf[2];
  {
    const ushort* qrow = Qg + (size_t)(q0 + w * 16 + l16) * HD;
    qf[0] = *(const short8*)(qrow + quad * 8);
    qf[1] = *(const short8*)(qrow + 32 + quad * 8);
  }

  const int row = tid >> 2;
  const int c0  = (tid & 3) * 16;
  const ushort* Kbase = Kg + (size_t)row * HD + c0;   // + kt*64*HD
  const ushort* Vbase = Vg + (size_t)row * TT + c0;   // + kt*64

  float lsp[4] = {0.f, 0.f, 0.f, 0.f};   // per-lane partial row sums, q = l16
  f32x4 O[4];
#pragma unroll
  for (int ni = 0; ni < 4; ++ni) O[ni] = (f32x4){0.f, 0.f, 0.f, 0.f};

  auto compute_tile = [&](int kt) {
    // S^T = K . Q^T : lane(quad,l16) holds keys ni*16+quad*4+r at q-col l16
    f32x4 s[4];
#pragma unroll
    for (int ni = 0; ni < 4; ++ni) s[ni] = (f32x4){0.f, 0.f, 0.f, 0.f};
#pragma unroll
    for (int ks = 0; ks < 2; ++ks) {
#pragma unroll
      for (int ni = 0; ni < 4; ++ni) {
        short8 kb = *(const short8*)&Ks[(ni * 16 + l16) * LDA + ks * 32 + quad * 8];
        s[ni] = __builtin_amdgcn_mfma_f32_16x16x32_bf16(kb, qf[ks], s[ni], 0, 0, 0);
      }
    }
    if (kt == qt) {   // diagonal tile: mask key > q (both local to the tile)
      const int qq = w * 16 + l16;
#pragma unroll
      for (int ni = 0; ni < 4; ++ni) {
#pragma unroll
        for (int r = 0; r < 4; ++r)
          if (ni * 16 + quad * 4 + r > qq) s[ni][r] = -__builtin_inff();
      }
    }
    // p = 2^s; keys are register-contiguous -> pack pairs + b64 writes
#pragma unroll
    for (int ni = 0; ni < 4; ++ni) {
      union { float f; uint32_t u; } p0, p1, p2, p3;
      p0.f = exp2f(s[ni][0]); p1.f = exp2f(s[ni][1]);
      p2.f = exp2f(s[ni][2]); p3.f = exp2f(s[ni][3]);
      lsp[ni] += (p0.f + p1.f) + (p2.f + p3.f);
      uint2 dw;
      dw.x = pack2(p0.u, p1.u);
      dw.y = pack2(p2.u, p3.u);
      *(uint2*)&Ps[w][l16 * LDA + ni * 16 + quad * 4] = dw;   // P[q=l16][keys]
    }
    // O += P V  (A = P from wave-private LDS, B = Vt)
#pragma unroll
    for (int ks = 0; ks < 2; ++ks) {
      short8 a = *(const short8*)&Ps[w][l16 * LDA + ks * 32 + quad * 8];
#pragma unroll
      for (int ni = 0; ni < 4; ++ni) {
        short8 vb = *(const short8*)&Vts[(ni * 16 + l16) * LDA + ks * 32 + quad * 8];
        O[ni] = __builtin_amdgcn_mfma_f32_16x16x32_bf16(a, vb, O[ni], 0, 0, 0);
      }
    }
  };

  // named 2-set prefetch (no dynamic register indexing)
  short8 ak0, ak1, av0, av1;
  short8 bk0, bk1, bv0, bv1;
  ak0 = *(const short8*)(Kbase);
  ak1 = *(const short8*)(Kbase + 8);
  av0 = *(const short8*)(Vbase);
  av1 = *(const short8*)(Vbase + 8);

  for (int kt = 0; kt <= qt; ) {
    __syncthreads();
    *(short8*)&Ks[row * LDA + c0]      = ak0;
    *(short8*)&Ks[row * LDA + c0 + 8]  = ak1;
    *(short8*)&Vts[row * LDA + c0]     = av0;
    *(short8*)&Vts[row * LDA + c0 + 8] = av1;
    if (kt + 1 <= qt) {
      const size_t ko_ = (size_t)(kt + 1) * 64 * HD;
      bk0 = *(const short8*)(Kbase + ko_);
      bk1 = *(const short8*)(Kbase + ko_ + 8);
      bv0 = *(const short8*)(Vbase + (kt + 1) * 64);
      bv1 = *(const short8*)(Vbase + (kt + 1) * 64 + 8);
    }
    __syncthreads();
    compute_tile(kt);
    ++kt;
    if (kt > qt) break;

    __syncthreads();
    *(short8*)&Ks[row * LDA + c0]      = bk0;
    *(short8*)&Ks[row * LDA + c0 + 8]  = bk1;
    *(short8*)&Vts[row * LDA + c0]     = bv0;
    *(short8*)&Vts[row * LDA + c0 + 8] = bv1;
    if (kt + 1 <= qt) {
      const size_t ko_ = (size_t)(kt + 1) * 64 * HD;
      ak0 = *(const short8*)(Kbase + ko_);
      ak1 = *(const short8*)(Kbase + ko_ + 8);
      av0 = *(const short8*)(Vbase + (kt + 1) * 64);
      av1 = *(const short8*)(Vbase + (kt + 1) * 64 + 8);
    }
    __syncthreads();
    compute_tile(kt);
    ++kt;
  }

  // reduce ls across quads (each lane then holds total for q = l16)
  float lst = (lsp[0] + lsp[1]) + (lsp[2] + lsp[3]);
  lst += __shfl_xor(lst, 16);
  lst += __shfl_xor(lst, 32);

#pragma unroll
  for (int r = 0; r < 4; ++r) {
    const float inv = 1.0f / __shfl(lst, (lane & 48) | (quad * 4 + r));
    const int t = q0 + w * 16 + quad * 4 + r;
#pragma unroll
    for (int ni = 0; ni < 4; ++ni) {
      out[((size_t)(b * TT + t)) * EMB + h * HD + ni * 16 + l16] = f2bf(O[ni][r] * inv);
    }
  }
}

// ---------------------------------------------------------------------------
// Output projection: 128m x 64n tiles (32 mt x 16 nt = 512 blocks, 2/CU).
// Halves Wo L2 traffic vs tileM=64 (Wo re-read by 32 m-tiles, not 64).
// BK=64, 3-set distance-2 rotation. Wave w owns rows [w*32, w*32+32).
// ---------------------------------------------------------------------------
template<bool WBF>
__device__ __forceinline__ void proj_core(const ushort* __restrict__ A,
                                          const void* __restrict__ Wo,
                                          int m0, int n0,
                                          ushort* As, ushort* Ws,
                                          f32x4 acc[2][4]) {
  const int tid  = threadIdx.x;
  const int w    = tid >> 6;
  const int lane = tid & 63;
  const int quad = lane >> 4;
  const int l16  = lane & 15;
  const int arow = tid >> 1;            // 0..127
  const int acol = (tid & 1) * 32;      // 32 bf16 cols
  const int brow = tid >> 2;            // 0..63
  const int bcol = (tid & 3) * 16;      // 16 cols

  const size_t aoff = (size_t)(m0 + arow) * EMB + acol;
  const size_t boff = (size_t)(n0 + brow) * EMB + bcol;

  short8 ab[3][4];   // A: 32 bf16
  short8 wb[3][2];   // W bf16: 16
  f32x4  wf[3][4];   // W fp32: 16

#pragma unroll
  for (int s = 0; s < 2; ++s) {
#pragma unroll
    for (int i = 0; i < 4; ++i)
      ab[s][i] = *(const short8*)(A + aoff + 64 * s + 8 * i);
    if constexpr (WBF) {
      wb[s][0] = *(const short8*)((const ushort*)Wo + boff + 64 * s);
      wb[s][1] = *(const short8*)((const ushort*)Wo + boff + 64 * s + 8);
    } else {
#pragma unroll
      for (int i = 0; i < 4; ++i)
        wf[s][i] = *(const f32x4*)((const float*)Wo + boff + 64 * s + 4 * i);
    }
  }

#pragma unroll
  for (int it = 0; it < 16; ++it) {
    const int k0 = it * 64;
    const int cur = it % 3, nxt = (it + 2) % 3;
    __syncthreads();
#pragma unroll
    for (int i = 0; i < 4; ++i)
      *(short8*)&As[arow * LDP + acol + 8 * i] = ab[cur][i];
    if constexpr (WBF) {
      *(short8*)&Ws[brow * LDP + bcol]     = wb[cur][0];
      *(short8*)&Ws[brow * LDP + bcol + 8] = wb[cur][1];
    } else {
      *(short8*)&Ws[brow * LDP + bcol]     = pack8(wf[cur][0], wf[cur][1]);
      *(short8*)&Ws[brow * LDP + bcol + 8] = pack8(wf[cur][2], wf[cur][3]);
    }
    if (it + 2 < 16) {
      const int kn = k0 + 128;
#pragma unroll
      for (int i = 0; i < 4; ++i)
        ab[nxt][i] = *(const short8*)(A + aoff + kn + 8 * i);
      if constexpr (WBF) {
        wb[nxt][0] = *(const short8*)((const ushort*)Wo + boff + kn);
        wb[nxt][1] = *(const short8*)((const ushort*)Wo + boff + kn + 8);
      } else {
#pragma unroll
        for (int i = 0; i < 4; ++i)
          wf[nxt][i] = *(const f32x4*)((const float*)Wo + boff + kn + 4 * i);
      }
    }
    __syncthreads();

#pragma unroll
    for (int ks = 0; ks < 2; ++ks) {
      short8 a_[2], b_[4];
#pragma unroll
      for (int i = 0; i < 2; ++i)
        a_[i] = *(const short8*)&As[(w * 32 + i * 16 + l16) * LDP + ks * 32 + quad * 8];
#pragma unroll
      for (int i = 0; i < 4; ++i)
        b_[i] = *(const short8*)&Ws[(i * 16 + l16) * LDP + ks * 32 + quad * 8];
#pragma unroll
      for (int mi = 0; mi < 2; ++mi)
#pragma unroll
        for (int ni = 0; ni < 4; ++ni)
          acc[mi][ni] = __builtin_amdgcn_mfma_f32_16x16x32_bf16(a_[mi], b_[ni], acc[mi][ni], 0, 0, 0);
    }
  }
}

__global__ __launch_bounds__(256) void proj_pipe(const ushort* __restrict__ A,
                                                 const void* __restrict__ Wo,
                                                 const void* __restrict__ bo,
                                                 void* __restrict__ out,
                                                 const int* __restrict__ flag) {
  __shared__ __align__(16) ushort As[128 * LDP];
  __shared__ __align__(16) ushort Ws[64 * LDP];
  const int nt = blockIdx.x & 15;        // consecutive bids -> round-robin XCDs
  const int mt = blockIdx.x >> 4;        // 0..31 (128-row tiles)
  const int n0 = nt * 64;
  const int m0 = mt * 128;

  f32x4 acc[2][4];
#pragma unroll
  for (int i = 0; i < 2; ++i)
#pragma unroll
    for (int jj = 0; jj < 4; ++jj) acc[i][jj] = (f32x4){0.f, 0.f, 0.f, 0.f};

  const int isbf = *flag;
  if (isbf) proj_core<true >(A, Wo, m0, n0, As, Ws, acc);
  else      proj_core<false>(A, Wo, m0, n0, As, Ws, acc);

  const int tid  = threadIdx.x;
  const int w    = tid >> 6;
  const int lane = tid & 63;
  const int quad = lane >> 4;
  const int l16  = lane & 15;

#pragma unroll
  for (int ni = 0; ni < 4; ++ni) {
    const int n = n0 + ni * 16 + l16;
    const float bv_ = isbf ? bf2f(((const ushort*)bo)[n]) : ((const float*)bo)[n];
#pragma unroll
    for (int mi = 0; mi < 2; ++mi) {
#pragma unroll
      for (int r = 0; r < 4; ++r) {
        const int m = m0 + w * 32 + mi * 16 + quad * 4 + r;
        const float v = acc[mi][ni][r] + bv_;
        if (isbf) ((ushort*)out)[(size_t)m * EMB + n] = f2bf(v);
        else      ((float*) out)[(size_t)m * EMB + n] = v;
      }
    }
  }
}

// ---------------------------------------------------------------------------
extern "C" void kernel_launch(void* const* d_in, const int* in_sizes, int n_in,
                              void* d_out, int out_size, void* d_ws, size_t ws_size,
                              hipStream_t stream) {
  const void* x  = d_in[0];
  const void* Wq = d_in[1];
  const void* bq = d_in[2];
  const void* Wk = d_in[3];
  const void* bk = d_in[4];
  const void* Wv = d_in[5];
  const void* bv = d_in[6];
  const void* Wo = d_in[7];
  const void* bo = d_in[8];

  int* flag = (int*)d_ws;
  ushort* base = (ushort*)((char*)d_ws + 256);

  // ws layout (33.56 MB budget):
  //   q:[0,ELX) k:[ELX,2ELX) vt:[2ELX,3ELX)
  //   w3 (3*ELW, dead after qkv) and o (ELX) share [3ELX,4ELX)
  ushort* q_ws  = base;
  ushort* k_ws  = q_ws + ELX;
  ushort* vt_ws = k_ws + ELX;
  ushort* w3    = vt_ws + ELX;
  ushort* o_ws  = vt_ws + ELX;

  detect_dtype<<<dim3(1), dim3(64), 0, stream>>>((const uint32_t*)x, flag);
  convert3<<<dim3(1536), dim3(256), 0, stream>>>(Wq, Wk, Wv, w3, flag);
  qkv_pipe<<<dim3(1536), dim3(256), 0, stream>>>(x, w3, bq, bk, bv,
                                                 q_ws, k_ws, vt_ws, flag);
  attn3<<<dim3(1024), dim3(256), 0, stream>>>(q_ws, k_ws, vt_ws, o_ws);
  proj_pipe<<<dim3(512), dim3(256), 0, stream>>>(o_ws, Wo, bo, d_out, flag);
}